// Round 7
// baseline (242.930 us; speedup 1.0000x reference)
//
#include <hip/hip_runtime.h>
#include <stdint.h>

// RNN: h_t = tanh(x_t W_ih^T + b_ih + b_hh + h_{t-1} W_hh^T)
// out[b,t] = W_fc . h_t + b_fc ;  hidden = h_T.  B=8192, T=512, I=H=7. fp32.
//
// R7 = R6 (asm-pinned prefetch, DPP recurrence) + TLP: 16 lanes per chain,
// two 8-lane subgroups compute the SAME chain redundantly. 131072 threads =
// 2048 waves = 2 waves/SIMD -> HW TLP fills the tanh/DPP dep bubbles that
// 1 wave/SIMD left exposed (R6: 323 cyc/step = 152 issue + 171 stall).
// All cross-lane DPP stays within each 8-lane subgroup -> unchanged math.

#define B_TOTAL 8192
#define T_STEPS 512

#define DPP_QUAD0 0x00        // quad_perm [0,0,0,0]
#define DPP_QUAD1 0x55        // quad_perm [1,1,1,1]
#define DPP_QUAD2 0xAA        // quad_perm [2,2,2,2]
#define DPP_QUAD3 0xFF        // quad_perm [3,3,3,3]
#define DPP_XOR1  0xB1        // quad_perm [1,0,3,2]
#define DPP_XOR2  0x4E        // quad_perm [2,3,0,1]
#define DPP_HM    0x141       // row_half_mirror

template <int CTRL>
__device__ __forceinline__ float dpp_mov(float v) {
    int s = __float_as_int(v);
    return __int_as_float(__builtin_amdgcn_update_dpp(s, s, CTRL, 0xF, 0xF, true));
}

__device__ __forceinline__ float tanh_fast(float a) {
    float e = __builtin_amdgcn_exp2f(a * 2.8853900817779268f);
    float r = __builtin_amdgcn_rcpf(e + 1.0f);
    return __builtin_fmaf(-2.0f, r, 1.0f);
}

typedef float v4f __attribute__((ext_vector_type(4)));

struct XChunk { v4f v[14]; };   // 8 steps * 7 floats = 56 floats = 224 B

// Issue 14 async 16B loads; results land in the asm-def'd VGPRs at vmcnt.
__device__ __forceinline__ void chunk_issue(XChunk& ch, const float* base) {
    #pragma unroll
    for (int i = 0; i < 14; ++i)
        asm volatile("global_load_dwordx4 %0, %1, off offset:%2"
                     : "=v"(ch.v[i]) : "v"(base), "i"(16 * i));
}

// Wait until at most N VMEM ops outstanding; "+v" operands force ordering.
#define CHUNK_WAIT(ch, N)                                                     \
    asm volatile("s_waitcnt vmcnt(" #N ")"                                    \
        : "+v"((ch).v[0]), "+v"((ch).v[1]), "+v"((ch).v[2]), "+v"((ch).v[3]), \
          "+v"((ch).v[4]), "+v"((ch).v[5]), "+v"((ch).v[6]), "+v"((ch).v[7]), \
          "+v"((ch).v[8]), "+v"((ch).v[9]), "+v"((ch).v[10]),                 \
          "+v"((ch).v[11]), "+v"((ch).v[12]), "+v"((ch).v[13]))

__global__ __launch_bounds__(256, 2) void rnn_kernel(
    const float* __restrict__ x,    // [B, T, I]
    const float* __restrict__ Wih,  // [H, I]
    const float* __restrict__ Whh,  // [H, H]
    const float* __restrict__ bih,  // [H]
    const float* __restrict__ bhh,  // [H]
    const float* __restrict__ Wfc,  // [1, H]
    const float* __restrict__ bfc,  // [1]
    float* __restrict__ out)        // [B*T] out, then [B*H] hidden
{
    const int tid  = threadIdx.x;
    const int k    = tid & 7;                 // h-row (7 = dummy)
    const int sub  = (tid >> 3) & 1;          // redundant subgroup 0/1
    const int b    = blockIdx.x * 16 + (tid >> 4);   // 16 lanes per chain
    const int quad = (tid >> 2) & 1;          // quad parity within 8-lane subgroup

    // ---- weights (before any asm prefetch is outstanding) ----
    float wih[7];
    float wa[4], wb[4];
    float bias = 0.0f, wfc_own = 0.0f;
    {
        float whh_row[8];
        #pragma unroll
        for (int i = 0; i < 8; ++i) whh_row[i] = 0.0f;
        if (k < 7) {
            #pragma unroll
            for (int i = 0; i < 7; ++i) {
                wih[i] = Wih[k * 7 + i];
                whh_row[i] = Whh[k * 7 + i];
            }
            bias = bih[k] + bhh[k];
            wfc_own = Wfc[k];
        } else {
            #pragma unroll
            for (int i = 0; i < 7; ++i) wih[i] = 0.0f;
        }
        #pragma unroll
        for (int j = 0; j < 4; ++j) {
            wa[j] = quad ? whh_row[4 + j] : whh_row[j];
            wb[j] = quad ? whh_row[j]     : whh_row[4 + j];
        }
    }
    const float bfcv = bfc[0];

    const float* xrow = x + (size_t)b * (T_STEPS * 7);   // 3584 floats
    float* outp = out + (size_t)b * T_STEPS;
    const bool store_out = (k == 7) && (sub == 0);       // one store per chain

    float a0 = 0.f, a1 = 0.f, a2 = 0.f, a3 = 0.f;
    float b0 = 0.f, b1 = 0.f, b2 = 0.f, b3 = 0.f;

    XChunk A, B;
    chunk_issue(A, xrow);            // chunk 0
    chunk_issue(B, xrow + 56);       // chunk 1

    auto do_chunk = [&](XChunk& buf, int c, const float* reload) {
        float u[8];
        {
            float xv[56];
            #pragma unroll
            for (int i = 0; i < 14; ++i) {
                xv[4 * i + 0] = buf.v[i].x; xv[4 * i + 1] = buf.v[i].y;
                xv[4 * i + 2] = buf.v[i].z; xv[4 * i + 3] = buf.v[i].w;
            }
            #pragma unroll
            for (int s = 0; s < 8; ++s) {
                const float* xs = &xv[s * 7];
                float p01 = __builtin_fmaf(wih[1], xs[1], wih[0] * xs[0]);
                float p23 = __builtin_fmaf(wih[3], xs[3], wih[2] * xs[2]);
                float p45 = __builtin_fmaf(wih[5], xs[5], wih[4] * xs[4]);
                float p6b = __builtin_fmaf(wih[6], xs[6], bias);
                u[s] = (p01 + p23) + (p45 + p6b);
            }
        }
        if (reload) chunk_issue(buf, reload);   // in flight across the 8 steps
        // Serial recurrence (b-values consumed last in the tree)
        float hs[8];
        #pragma unroll
        for (int s = 0; s < 8; ++s) {
            float p0 = __builtin_fmaf(wa[0], a0, u[s]);
            float p1 = __builtin_fmaf(wa[2], a2, wa[1] * a1);
            float p2 = __builtin_fmaf(wb[0], b0, wa[3] * a3);
            float p3 = __builtin_fmaf(wb[2], b2, wb[1] * b1);
            float p4 = wb[3] * b3;
            float acc = (p0 + p1) + (p2 + (p3 + p4));
            float hk = tanh_fast(acc);
            hs[s] = hk;
            a0 = dpp_mov<DPP_QUAD0>(hk);
            a1 = dpp_mov<DPP_QUAD1>(hk);
            a2 = dpp_mov<DPP_QUAD2>(hk);
            a3 = dpp_mov<DPP_QUAD3>(hk);
            b0 = dpp_mov<DPP_HM>(a0);
            b1 = dpp_mov<DPP_HM>(a1);
            b2 = dpp_mov<DPP_HM>(a2);
            b3 = dpp_mov<DPP_HM>(a3);
        }
        // Out-projection butterfly (ILP filler)
        float o[8];
        #pragma unroll
        for (int s = 0; s < 8; ++s) {
            float v = wfc_own * hs[s];
            v += dpp_mov<DPP_XOR1>(v);
            v += dpp_mov<DPP_XOR2>(v);
            v += dpp_mov<DPP_HM>(v);
            o[s] = v + bfcv;
        }
        if (store_out) {
            *(float4*)(outp + c * 8 + 0) = make_float4(o[0], o[1], o[2], o[3]);
            *(float4*)(outp + c * 8 + 4) = make_float4(o[4], o[5], o[6], o[7]);
        }
    };

    // Steady loop: chunks 0..61; reloads c+2 (<=62) and c+3 (<=63) always valid.
    #pragma unroll 1
    for (int c = 0; c < 62; c += 2) {
        CHUNK_WAIT(A, 14);                         // A(c) is oldest -> drained
        do_chunk(A, c, xrow + (c + 2) * 56);
        CHUNK_WAIT(B, 14);                         // B(c+1) oldest -> drained
        do_chunk(B, c + 1, xrow + (c + 3) * 56);
    }
    // Epilogue: chunks 62 (A) and 63 (B), no reloads.
    CHUNK_WAIT(A, 14);
    do_chunk(A, 62, nullptr);
    CHUNK_WAIT(B, 0);
    do_chunk(B, 63, nullptr);

    // hidden h_T: lane k's own value is a_{k&3} (both quads); one subgroup stores
    if (k < 7 && sub == 0) {
        int kk = k & 3;
        float hv = (kk == 0) ? a0 : (kk == 1) ? a1 : (kk == 2) ? a2 : a3;
        out[(size_t)B_TOTAL * T_STEPS + (size_t)b * 7 + k] = hv;
    }
}

extern "C" void kernel_launch(void* const* d_in, const int* in_sizes, int n_in,
                              void* d_out, int out_size, void* d_ws, size_t ws_size,
                              hipStream_t stream) {
    const float* x   = (const float*)d_in[0];
    const float* Wih = (const float*)d_in[1];
    const float* Whh = (const float*)d_in[2];
    const float* bih = (const float*)d_in[3];
    const float* bhh = (const float*)d_in[4];
    const float* Wfc = (const float*)d_in[5];
    const float* bfc = (const float*)d_in[6];
    float* out = (float*)d_out;

    // 8192 chains * 16 lanes (2 redundant 8-lane subgroups) = 131072 threads;
    // 512 blocks x 256 -> 2 blocks/CU -> 2 waves/SIMD (TLP fills dep bubbles).
    rnn_kernel<<<dim3(B_TOTAL / 16), dim3(256), 0, stream>>>(
        x, Wih, Whh, bih, bhh, Wfc, bfc, out);
}